// Round 2
// baseline (48.312 us; speedup 1.0000x reference)
//
#include <hip/hip_runtime.h>

#define TPB 192            // 3 waves; wave c owns channel c
#define CH4 65536          // float4 granules per 512x512 plane

static __device__ __forceinline__ void fma4(float4& a, float s, const float4& v) {
    a.x = fmaf(s, v.x, a.x);
    a.y = fmaf(s, v.y, a.y);
    a.z = fmaf(s, v.z, a.z);
    a.w = fmaf(s, v.w, a.w);
}
static __device__ __forceinline__ float4 cvt3(float ka, const float4& A,
                                              float kb, const float4& B,
                                              float kc, const float4& C) {
    float4 r;
    r.x = fmaf(ka, A.x, fmaf(kb, B.x, kc * C.x));
    r.y = fmaf(ka, A.y, fmaf(kb, B.y, kc * C.y));
    r.z = fmaf(ka, A.z, fmaf(kb, B.z, kc * C.z));
    r.w = fmaf(ka, A.w, fmaf(kb, B.w, kc * C.w));
    return r;
}
// granule swizzle: XOR bits 5:3 into 2:0 -> uniform over 8 b128 bank-groups
// for both lane->g (stride 1, +64) and lane->2g (stride 2) patterns
static __device__ __forceinline__ int swz(int g) { return g ^ ((g >> 3) & 7); }

__global__ __launch_bounds__(TPB) void jpeg_fused(
    const float* __restrict__ img,
    const float* __restrict__ Dd,
    const float* __restrict__ Di,
    const float* __restrict__ mask,
    float* __restrict__ out)
{
    // double-buffered one-row staging: [buf][channel][128 granules] = 12 KB
    __shared__ float4 buf[2][3][128];

    const int tid = threadIdx.x;
    const int wg  = blockIdx.x;
    const int b   = wg >> 6;     // batch
    const int rb  = wg & 63;     // 8-row strip

    const int c   = tid >> 6;    // wave-uniform channel
    const int blk = tid & 63;    // 8x8 block column
    const int cs  = __builtin_amdgcn_readfirstlane(c);

    // swizzled LDS granule indices
    const int sa = swz(blk);          // cooperative row write / phase-B read, lo
    const int sb = swz(64 + blk);     // ... hi
    const int sc = swz(2 * blk);      // block-column read / phase-B write, lo
    const int sd = swz(2 * blk + 1);  // ... hi

    const size_t tbase = ((size_t)b * 1536 + (size_t)rb * 8) * 128; // granules
    const float4* in4  = reinterpret_cast<const float4*>(img) + tbase;
    float4*       out4 = reinterpret_cast<float4*>(out) + tbase;

    // per-channel color coefficients (wave-uniform scalars)
    float kr, kg, kb;            // rgb -> (this channel of yuv)
    float ky, ku, kv;            // yuv -> (this channel of rgb)
    if (cs == 0)      { kr = 0.299f;    kg = 0.587f;    kb = 0.114f;
                        ky = 1.f;       ku = 0.f;       kv = 1.13983f; }
    else if (cs == 1) { kr = -0.14713f; kg = -0.28886f; kb = 0.436f;
                        ky = 1.f;       ku = -0.39465f; kv = -0.5806f; }
    else              { kr = 0.615f;    kg = -0.51499f; kb = -0.10001f;
                        ky = 1.f;       ku = 2.03211f;  kv = 0.f; }

    const float* __restrict__ M = mask + (size_t)cs * (512 * 512); // top-left 8x8 tile

    // ---------------- Phase A: stream rows in, build YUV block in registers ----
    const float4* planeP = in4 + (size_t)c * CH4;  // wave c loads channel-c plane
    float4 xlo[8], xhi[8];

    float4 pf0 = planeP[blk];
    float4 pf1 = planeP[64 + blk];
    #pragma unroll
    for (int k = 0; k < 8; ++k) {
        float4* wb = &buf[k & 1][c][0];
        wb[sa] = pf0;
        wb[sb] = pf1;
        if (k < 7) {                       // prefetch next row; stays in flight
            pf0 = planeP[(k + 1) * 128 + blk];
            pf1 = planeP[(k + 1) * 128 + 64 + blk];
        }
        asm volatile("s_waitcnt lgkmcnt(0)\ns_barrier" ::: "memory");
        const float4 R0 = buf[k & 1][0][sc];
        const float4 G0 = buf[k & 1][1][sc];
        const float4 B0 = buf[k & 1][2][sc];
        const float4 R1 = buf[k & 1][0][sd];
        const float4 G1 = buf[k & 1][1][sd];
        const float4 B1 = buf[k & 1][2][sd];
        xlo[k] = cvt3(kr, R0, kg, G0, kb, B0);
        xhi[k] = cvt3(kr, R1, kg, G1, kb, B1);
    }

    // ---------------- DCT -> mask -> IDCT, all in registers ----------------
    float4 zlo[8], zhi[8];
    #pragma unroll
    for (int k = 0; k < 8; ++k) {
        float4 tlo = make_float4(0.f, 0.f, 0.f, 0.f);
        float4 thi = make_float4(0.f, 0.f, 0.f, 0.f);
        #pragma unroll
        for (int n = 0; n < 8; ++n) {
            const float d = Dd[k * 8 + n];
            fma4(tlo, d, xlo[n]);
            fma4(thi, d, xhi[n]);
        }
        const float t[8] = {tlo.x, tlo.y, tlo.z, tlo.w, thi.x, thi.y, thi.z, thi.w};
        float z[8];
        #pragma unroll
        for (int l = 0; l < 8; ++l) {
            float acc = 0.f;
            #pragma unroll
            for (int m = 0; m < 8; ++m) acc = fmaf(t[m], Dd[l * 8 + m], acc);
            z[l] = acc * M[k * 512 + l];
        }
        zlo[k] = make_float4(z[0], z[1], z[2], z[3]);
        zhi[k] = make_float4(z[4], z[5], z[6], z[7]);
    }

    float4 olo[8], ohi[8];
    #pragma unroll
    for (int k = 0; k < 8; ++k) {
        float4 tlo = make_float4(0.f, 0.f, 0.f, 0.f);
        float4 thi = make_float4(0.f, 0.f, 0.f, 0.f);
        #pragma unroll
        for (int n = 0; n < 8; ++n) {
            const float d = Di[k * 8 + n];
            fma4(tlo, d, zlo[n]);
            fma4(thi, d, zhi[n]);
        }
        const float t[8] = {tlo.x, tlo.y, tlo.z, tlo.w, thi.x, thi.y, thi.z, thi.w};
        float z[8];
        #pragma unroll
        for (int l = 0; l < 8; ++l) {
            float acc = 0.f;
            #pragma unroll
            for (int m = 0; m < 8; ++m) acc = fmaf(t[m], Di[l * 8 + m], acc);
            z[l] = acc;
        }
        olo[k] = make_float4(z[0], z[1], z[2], z[3]);
        ohi[k] = make_float4(z[4], z[5], z[6], z[7]);
    }

    // ---------------- Phase B: stream rows out through LDS ----------------
    float4* plane_out = out4 + (size_t)c * CH4;
    #pragma unroll
    for (int k = 0; k < 8; ++k) {
        float4* wb = &buf[k & 1][c][0];
        wb[sc] = olo[k];
        wb[sd] = ohi[k];
        asm volatile("s_waitcnt lgkmcnt(0)\ns_barrier" ::: "memory");
        const float4 Y0 = buf[k & 1][0][sa];
        const float4 U0 = buf[k & 1][1][sa];
        const float4 V0 = buf[k & 1][2][sa];
        const float4 Y1 = buf[k & 1][0][sb];
        const float4 U1 = buf[k & 1][1][sb];
        const float4 V1 = buf[k & 1][2][sb];
        plane_out[k * 128 + blk]      = cvt3(ky, Y0, ku, U0, kv, V0);
        plane_out[k * 128 + 64 + blk] = cvt3(ky, Y1, ku, U1, kv, V1);
    }
}

extern "C" void kernel_launch(void* const* d_in, const int* in_sizes, int n_in,
                              void* d_out, int out_size, void* d_ws, size_t ws_size,
                              hipStream_t stream) {
    const float* img  = (const float*)d_in[0];
    const float* Dd   = (const float*)d_in[1];
    const float* Di   = (const float*)d_in[2];
    const float* mask = (const float*)d_in[3];
    float* out = (float*)d_out;

    const int B = in_sizes[0] / (3 * 512 * 512);   // 32
    dim3 grid(B * 64);                              // one wg per (batch, 8-row strip)
    dim3 block(TPB);
    hipLaunchKernelGGL(jpeg_fused, grid, block, 0, stream, img, Dd, Di, mask, out);
}